// Round 2
// baseline (583.592 us; speedup 1.0000x reference)
//
#include <hip/hip_runtime.h>

#define BB 512
#define TT 256

typedef __attribute__((ext_vector_type(8)))  short bf8;   // 8 bf16 in 4 VGPRs
typedef __attribute__((ext_vector_type(16))) float f16v;  // MFMA 32x32 acc
typedef __attribute__((ext_vector_type(4)))  float f4v;

#define MFMA(a,b,c) __builtin_amdgcn_mfma_f32_32x32x16_bf16((a),(b),(c),0,0,0)

static __device__ __forceinline__ unsigned short f2bf_rne(float x) {
    unsigned u = __builtin_bit_cast(unsigned, x);
    return (unsigned short)((u + 0x7FFFu + ((u >> 16) & 1u)) >> 16);
}
static __device__ __forceinline__ float bf2f(unsigned short h) {
    unsigned u = ((unsigned)h) << 16;
    return __builtin_bit_cast(float, u);
}
// truncation-based hi/lo split: |x - (hi+lo)| <~ 2^-17 |x|
static __device__ __forceinline__ void tsplit(float x, short& hi, short& lo) {
    unsigned u = __builtin_bit_cast(unsigned, x);
    hi = (short)(u >> 16);
    float hf = __builtin_bit_cast(float, u & 0xFFFF0000u);
    float l  = x - hf;
    lo = (short)(__builtin_bit_cast(unsigned, l) >> 16);
}

// C-layout result X (lane (c,h) reg r = X[(r&3)+8(r>>2)+4h][c]) ->
// MFMA B-frag of X (== A-frag of X^T): lane (c,h) elem j of kk = X[16kk+8h+j][c].
// Data movement built ONLY from v5-verified primitives: the two half-waves need
// different registers from their partner, so select-before-shuffle captures the
// whole exchange in 8 bpermutes (v5's verified fr[] build used 16).
static __device__ __forceinline__ void cfrag(const f16v X, const bool hb,
        bf8& F0h, bf8& F0l, bf8& F1h, bf8& F1l) {
    float fr0[8], fr1[8];
    #pragma unroll
    for (int j = 0; j < 4; ++j) {
        float t0 = hb ? X[j]    : X[4+j];
        float r0 = __shfl_xor(t0, 32, 64);
        fr0[j]   = hb ? r0      : X[j];
        fr0[4+j] = hb ? X[4+j]  : r0;
        float t1 = hb ? X[8+j]  : X[12+j];
        float r1 = __shfl_xor(t1, 32, 64);
        fr1[j]   = hb ? r1      : X[8+j];
        fr1[4+j] = hb ? X[12+j] : r1;
    }
    #pragma unroll
    for (int j = 0; j < 8; ++j) {
        short hi, lo;
        tsplit(fr0[j], hi, lo); F0h[j] = hi; F0l[j] = lo;
        tsplit(fr1[j], hi, lo); F1h[j] = hi; F1l[j] = lo;
    }
}

// One chain per wave; single-wave block => no __syncthreads anywhere.
// Step:  P_p = (F P F^T + Q) - W Sinv W^T,  W = F P H^T.
// v7 = v6 dataflow (no LDS on the P-path: PHt computed directly so N/T frags
// come from registers; Smeas/resid broadcast via readlane) with cfrag built
// from verified shfl_xor instead of permlane32_swap (round-1 NaN suspect).
__global__ __launch_bounds__(64, 1)
void kalman_v7(const float* __restrict__ obs,
               const float* __restrict__ Fg,
               const float* __restrict__ Qg,
               const float* __restrict__ Hg,
               const float* __restrict__ Rg,
               const float* __restrict__ im,
               const float* __restrict__ ic,
               float* __restrict__ out)
{
    __shared__ __align__(16) float sFH[36*40];   // rows 0-31: F, rows 32-35: H
    __shared__ __align__(16) float sm[32];

    const int lane = threadIdx.x;
    const int b    = blockIdx.x;
    const int c    = lane & 31;
    const int h    = lane >> 5;
    const bool hb  = (h != 0);

    bf8 Fh[2], Fl[2], Hh[2], Hl[2];
    #pragma unroll
    for (int kk = 0; kk < 2; ++kk) {
        #pragma unroll
        for (int j = 0; j < 8; ++j) {
            int k = kk*16 + h*8 + j;
            float f = Fg[c*32 + k];
            unsigned short fh = f2bf_rne(f);
            Fh[kk][j] = (short)fh;
            Fl[kk][j] = (short)f2bf_rne(f - bf2f(fh));
            float hv = (c < 4) ? Hg[c*32 + k] : 0.f;
            unsigned short hh = f2bf_rne(hv);
            Hh[kk][j] = (short)hh;
            Hl[kk][j] = (short)f2bf_rne(hv - bf2f(hh));
        }
    }

    f16v Qc, P;
    #pragma unroll
    for (int reg = 0; reg < 16; ++reg) {
        int row = (reg & 3) + 8*(reg >> 2) + 4*h;
        Qc[reg] = Qg[row*32 + c];
        P[reg]  = ic[(size_t)b*1024 + row*32 + c];
    }
    float Rc[4] = {0.f, 0.f, 0.f, 0.f};
    if (c < 4) {
        #pragma unroll
        for (int m = 0; m < 4; ++m) Rc[m] = Rg[m*4 + c];
    }

    #pragma unroll
    for (int e = lane; e < 1024; e += 64) sFH[(e >> 5)*40 + (e & 31)] = Fg[e];
    #pragma unroll
    for (int e = lane; e < 128; e += 64) sFH[(32 + (e >> 5))*40 + (e & 31)] = Hg[e];
    if (lane < 32) sm[lane] = im[b*32 + lane];

    const float* dotrow = &sFH[(lane < 32 ? lane : (32 + (lane & 3))) * 40];
    const bool yl = (lane >= 32 && lane < 36);
    const float* obsp = obs + (size_t)b*TT*4 + (yl ? (lane - 32) : 0);
    float* om = out;
    float* oc = out + (size_t)TT * BB * 4;

    // software-pipelined observation load (consumed one step later)
    float yv = yl ? obsp[0] : 0.f;

    for (int t = 0; t < TT; ++t) {
        // issue next step's obs load NOW; consumed ~full step later
        float yv_nxt = (yl && t + 1 < TT) ? obsp[(t + 1) * 4] : 0.f;

        // lanes<32: (F m)[lane];  lanes>=32: (H m)[lane&3]  (reads sm written last step)
        float dotv = 0.f;
        #pragma unroll
        for (int q = 0; q < 8; ++q) {
            f4v a = *(const f4v*)&dotrow[4*q];
            f4v mv = *(const f4v*)&sm[4*q];
            dotv += a.x*mv.x + a.y*mv.y + a.z*mv.z + a.w*mv.w;
        }

        // P frag via lane^32 exchange (P symmetric: B-frag == A-frag)
        bf8 Ph0, Pl0, Ph1, Pl1;
        cfrag(P, hb, Ph0, Pl0, Ph1, Pl1);

        // group 1, solve arm first: PHt = P*H^T  (cols c>=4 are exact zeros)
        f16v pA = 0.0f, pB = 0.0f;
        pA = MFMA(Ph0, Hh[0], pA);  pB = MFMA(Ph1, Hh[1], pB);
        pA = MFMA(Ph0, Hl[0], pA);  pB = MFMA(Ph1, Hl[1], pB);
        pA = MFMA(Pl0, Hh[0], pA);  pB = MFMA(Pl1, Hh[1], pB);

        // prediction arm: T1 = P*F^T
        f16v tA = 0.0f, tB = 0.0f;
        tA = MFMA(Ph0, Fh[0], tA);  tB = MFMA(Ph1, Fh[1], tB);
        tA = MFMA(Ph0, Fl[0], tA);  tB = MFMA(Ph1, Fl[1], tB);
        tA = MFMA(Pl0, Fh[0], tA);  tB = MFMA(Pl1, Fh[1], tB);

        // N-frags straight from registers (was: sPN LDS round trip)
        f16v PHs = pA + pB;
        bf8 N0h, N0l, N1h, N1l;
        cfrag(PHs, hb, N0h, N0l, N1h, N1l);

        // Smeas = H*PHt  (issue first: Cramer wants it earliest)
        f16v sA = 0.0f, sB = 0.0f;
        sA = MFMA(Hh[0], N0h, sA);  sB = MFMA(Hh[1], N1h, sB);
        sA = MFMA(Hh[0], N0l, sA);  sB = MFMA(Hh[1], N1l, sB);
        sA = MFMA(Hl[0], N0h, sA);  sB = MFMA(Hl[1], N1h, sB);

        // W^T = (HP)*F^T   (N as A-frag == A-frag of PHt^T == HP)
        f16v wA = 0.0f, wB = 0.0f;
        wA = MFMA(N0h, Fh[0], wA);  wB = MFMA(N1h, Fh[1], wB);
        wA = MFMA(N0h, Fl[0], wA);  wB = MFMA(N1h, Fl[1], wB);
        wA = MFMA(N0l, Fh[0], wA);  wB = MFMA(N1l, Fh[1], wB);

        // T-frags straight from registers (was: sT1 LDS round trip)
        f16v Tp = tA + tB;
        bf8 T0h, T0l, T1h_, T1l_;
        cfrag(Tp, hb, T0h, T0l, T1h_, T1l_);

        // Z = F*T1 + Q
        f16v zA = Qc, zB = 0.0f;
        zA = MFMA(Fh[0], T0h, zA);  zB = MFMA(Fh[1], T1h_, zB);
        zA = MFMA(Fh[0], T0l, zA);  zB = MFMA(Fh[1], T1l_, zB);
        zA = MFMA(Fl[0], T0h, zA);  zB = MFMA(Fl[1], T1l_, zB);

        // outputs
        float Smr[4];
        #pragma unroll
        for (int m = 0; m < 4; ++m) Smr[m] = sA[m] + sB[m] + Rc[m];
        if (lane < 32 && c < 4) {
            #pragma unroll
            for (int m = 0; m < 4; ++m)
                oc[(((size_t)t*BB + b)*4 + m)*4 + c] = Smr[m];
        }
        float residv = yv - dotv;                 // valid on lanes 32..35
        if (yl) om[((size_t)t*BB + b)*4 + (lane - 32)] = dotv;

        if (t == TT - 1) break;
        yv = yv_nxt;

        // Smeas broadcast via readlane (was: sS LDS round trip). S[4m+c] = S[m][c].
        const float S0  = __shfl(Smr[0], 0, 64);
        const float S1  = __shfl(Smr[0], 1, 64);
        const float S2  = __shfl(Smr[0], 2, 64);
        const float S3  = __shfl(Smr[0], 3, 64);
        const float S4  = __shfl(Smr[1], 0, 64);
        const float S5  = __shfl(Smr[1], 1, 64);
        const float S6  = __shfl(Smr[1], 2, 64);
        const float S7  = __shfl(Smr[1], 3, 64);
        const float S8  = __shfl(Smr[2], 0, 64);
        const float S9  = __shfl(Smr[2], 1, 64);
        const float S10 = __shfl(Smr[2], 2, 64);
        const float S11 = __shfl(Smr[2], 3, 64);
        const float S12 = __shfl(Smr[3], 0, 64);
        const float S13 = __shfl(Smr[3], 1, 64);
        const float S14 = __shfl(Smr[3], 2, 64);
        const float S15 = __shfl(Smr[3], 3, 64);

        // resid broadcast via readlane (was: sRes4 LDS round trip)
        const float rv0 = __shfl(residv, 32, 64);
        const float rv1 = __shfl(residv, 33, 64);
        const float rv2 = __shfl(residv, 34, 64);
        const float rv3 = __shfl(residv, 35, 64);

        float nG0, nG1, nG2, nG3, W0, W1, W2, W3;
        {
            const float A2323 = S10*S15 - S11*S14;
            const float A1323 = S9 *S15 - S11*S13;
            const float A1223 = S9 *S14 - S10*S13;
            const float A0323 = S8 *S15 - S11*S12;
            const float A0223 = S8 *S14 - S10*S12;
            const float A0123 = S8 *S13 - S9 *S12;
            const float A2313 = S6 *S15 - S7 *S14;
            const float A1313 = S5 *S15 - S7 *S13;
            const float A1213 = S5 *S14 - S6 *S13;
            const float A2312 = S6 *S11 - S7 *S10;
            const float A1312 = S5 *S11 - S7 *S9;
            const float A1212 = S5 *S10 - S6 *S9;
            const float A0313 = S4 *S15 - S7 *S12;
            const float A0213 = S4 *S14 - S6 *S12;
            const float A0312 = S4 *S11 - S7 *S8;
            const float A0212 = S4 *S10 - S6 *S8;
            const float A0113 = S4 *S13 - S5 *S12;
            const float A0112 = S4 *S9  - S5 *S8;

            const float i00 =  (S5*A2323 - S6*A1323 + S7*A1223);
            const float i10 = -(S4*A2323 - S6*A0323 + S7*A0223);
            const float i20 =  (S4*A1323 - S5*A0323 + S7*A0123);
            const float i30 = -(S4*A1223 - S5*A0223 + S6*A0123);
            const float i01 = -(S1*A2323 - S2*A1323 + S3*A1223);
            const float i11 =  (S0*A2323 - S2*A0323 + S3*A0223);
            const float i21 = -(S0*A1323 - S1*A0323 + S3*A0123);
            const float i31 =  (S0*A1223 - S1*A0223 + S2*A0123);
            const float i02 =  (S1*A2313 - S2*A1313 + S3*A1213);
            const float i12 = -(S0*A2313 - S2*A0313 + S3*A0213);
            const float i22 =  (S0*A1313 - S1*A0313 + S3*A0113);
            const float i32 = -(S0*A1213 - S1*A0213 + S2*A0113);
            const float i03 = -(S1*A2312 - S2*A1312 + S3*A1212);
            const float i13 =  (S0*A2312 - S2*A0312 + S3*A0212);
            const float i23 = -(S0*A1312 - S1*A0312 + S3*A0112);
            const float i33 =  (S0*A1212 - S1*A0212 + S2*A0112);

            const float det = S0*i00 + S1*i10 + S2*i20 + S3*i30;
            const float nid = -1.0f / det;   // nG = -W*Sinv

            W0 = wA[0] + wB[0];
            W1 = wA[1] + wB[1];
            W2 = wA[2] + wB[2];
            W3 = wA[3] + wB[3];

            nG0 = nid * (W0*i00 + W1*i10 + W2*i20 + W3*i30);
            nG1 = nid * (W0*i01 + W1*i11 + W2*i21 + W3*i31);
            nG2 = nid * (W0*i02 + W1*i12 + W2*i22 + W3*i32);
            nG3 = nid * (W0*i03 + W1*i13 + W2*i23 + W3*i33);
        }

        // rank-4 correction (h==1 lanes have W=0 -> nG=0 -> contribute zeros)
        bf8 Gh = (bf8)(short)0, Gl = (bf8)(short)0;
        bf8 Wbh = (bf8)(short)0, Wbl = (bf8)(short)0;
        {
            float ng[4] = {nG0, nG1, nG2, nG3};
            float wv[4] = {W0, W1, W2, W3};
            #pragma unroll
            for (int j2 = 0; j2 < 4; ++j2) {
                short hi, lo;
                tsplit(ng[j2], hi, lo);
                Gh[j2] = hi; Gl[j2] = lo;
                tsplit(wv[j2], hi, lo);
                Wbh[j2] = hi; Wbl[j2] = lo;
            }
        }
        f16v Pn = zA + zB;
        Pn = MFMA(Gh, Wbh, Pn);
        Pn = MFMA(Gh, Wbl, Pn);
        Pn = MFMA(Gl, Wbh, Pn);
        P = Pn;

        // mean: m_next = Fm - nG.resid   (lanes<32; dotv==Fm there)
        if (lane < 32)
            sm[lane] = dotv - (nG0*rv0 + nG1*rv1 + nG2*rv2 + nG3*rv3);
    }
}

extern "C" void kernel_launch(void* const* d_in, const int* in_sizes, int n_in,
                              void* d_out, int out_size, void* d_ws, size_t ws_size,
                              hipStream_t stream) {
    const float* obs       = (const float*)d_in[0];
    const float* F         = (const float*)d_in[1];
    const float* Q         = (const float*)d_in[2];
    const float* H         = (const float*)d_in[3];
    const float* R         = (const float*)d_in[4];
    const float* init_mean = (const float*)d_in[5];
    const float* init_cov  = (const float*)d_in[6];
    float* out = (float*)d_out;

    kalman_v7<<<BB, 64, 0, stream>>>(obs, F, Q, H, R, init_mean, init_cov, out);
}

// Round 3
// 480.234 us; speedup vs baseline: 1.2152x; 1.2152x over previous
//
#include <hip/hip_runtime.h>

#define BB 512
#define TT 256

typedef __attribute__((ext_vector_type(8)))  short bf8;   // 8 bf16 in 4 VGPRs
typedef __attribute__((ext_vector_type(16))) float f16v;  // MFMA 32x32 acc
typedef __attribute__((ext_vector_type(4)))  float f4v;

#define MFMA(a,b,c) __builtin_amdgcn_mfma_f32_32x32x16_bf16((a),(b),(c),0,0,0)

static __device__ __forceinline__ unsigned short f2bf_rne(float x) {
    unsigned u = __builtin_bit_cast(unsigned, x);
    return (unsigned short)((u + 0x7FFFu + ((u >> 16) & 1u)) >> 16);
}
static __device__ __forceinline__ float bf2f(unsigned short h) {
    unsigned u = ((unsigned)h) << 16;
    return __builtin_bit_cast(float, u);
}
// truncation-based hi/lo split: |x - (hi+lo)| <~ 2^-17 |x|
static __device__ __forceinline__ void tsplit(float x, short& hi, short& lo) {
    unsigned u = __builtin_bit_cast(unsigned, x);
    hi = (short)(u >> 16);
    float hf = __builtin_bit_cast(float, u & 0xFFFF0000u);
    float l  = x - hf;
    lo = (short)(__builtin_bit_cast(unsigned, l) >> 16);
}
// pi = swap bits 2 and 3 of a 5-bit row index (involution).
// Key identity: C-layout(D) reinterpreted with reg (j+8kk) as frag elem j of kk
// equals the A/B-frag of D^T*Pi  (same lane, same h -- ZERO cross-lane movement).
static __device__ __forceinline__ int pi(int i) {
    return (i & ~12) | ((i & 4) << 1) | ((i & 8) >> 1);
}
static __device__ __forceinline__ float rl(float x, int l) {
    return __builtin_bit_cast(float,
        __builtin_amdgcn_readlane(__builtin_bit_cast(unsigned, x), l));
}
// C-layout f32 (16 regs) -> bf16 hi/lo A/B operands; reg j+8kk -> elem j of kk.
static __device__ __forceinline__ void packfrag(const f16v X,
        bf8& h0, bf8& l0, bf8& h1, bf8& l1) {
    #pragma unroll
    for (int j = 0; j < 8; ++j) {
        short hi, lo;
        tsplit(X[j],     hi, lo);  h0[j] = hi;  l0[j] = lo;
        tsplit(X[8 + j], hi, lo);  h1[j] = hi;  l1[j] = lo;
    }
}

// One chain per wave; single-wave block => no __syncthreads anywhere.
// Step:  P_p = (F P F^T + Q) - W Sinv W^T,  W = F P H^T.
// v8: run the whole recursion similarity-transformed by Pi (hat(X) = Pi X Pi).
// Then every MFMA's C-layout output IS the next operand's frag (reg j+8kk ->
// elem j of kk), eliminating ALL ds_bpermute/LDS transposes from the P-path.
// Stages (all verified symbolically):
//   U1 = MFMA(stateA, Hplain)   = Pi*P*H^T
//   T  = MFMA(stateA, PiF)      = Pi*P*F^T*Pi
//   S  = MFMA(Hplain, U1-as-B)  = H*P*H^T            (exact, unpermuted)
//   Wt = MFMA(U1-as-A, PiF)     = W^T*Pi             (lane c: W'[c][m]=W[pi(c)][m])
//   Z  = MFMA(PiF, T-as-B) + hatQ = hat(F*P*F^T + Q)
//   corr = MFMA(nG'frag, W'frag)  = hat(nG*W^T)      -> state' = Z - corr
// Broadcasts via v_readlane (VALU); only LDS left is the 32-float mean vector.
__global__ __launch_bounds__(64, 1)
void kalman_v8(const float* __restrict__ obs,
               const float* __restrict__ Fg,
               const float* __restrict__ Qg,
               const float* __restrict__ Hg,
               const float* __restrict__ Rg,
               const float* __restrict__ im,
               const float* __restrict__ ic,
               float* __restrict__ out)
{
    __shared__ __align__(16) float sm[32];

    const int lane = threadIdx.x;
    const int b    = blockIdx.x;
    const int c    = lane & 31;
    const int h    = lane >> 5;

    // PiF (rows pi-permuted, cols plain) -- dual-use as A-frag and B-frag.
    // H plain (rows c<4), exactly as v7.
    bf8 Fh[2], Fl[2], Hh[2], Hl[2];
    #pragma unroll
    for (int kk = 0; kk < 2; ++kk) {
        #pragma unroll
        for (int j = 0; j < 8; ++j) {
            int k = kk*16 + h*8 + j;
            float f = Fg[pi(c)*32 + k];
            unsigned short fh = f2bf_rne(f);
            Fh[kk][j] = (short)fh;
            Fl[kk][j] = (short)f2bf_rne(f - bf2f(fh));
            float hv = (c < 4) ? Hg[c*32 + k] : 0.f;
            unsigned short hh = f2bf_rne(hv);
            Hh[kk][j] = (short)hh;
            Hl[kk][j] = (short)f2bf_rne(hv - bf2f(hh));
        }
    }

    // state P := hat(init_cov) = Pi*ic*Pi, Qc := hat(Q), both in C-layout.
    f16v Qc, P;
    #pragma unroll
    for (int reg = 0; reg < 16; ++reg) {
        int row = (reg & 3) + 8*(reg >> 2) + 4*h;
        Qc[reg] = Qg[pi(row)*32 + pi(c)];
        P[reg]  = ic[(size_t)b*1024 + pi(row)*32 + pi(c)];
    }
    float Rc[4] = {0.f, 0.f, 0.f, 0.f};
    if (c < 4) {
        #pragma unroll
        for (int m = 0; m < 4; ++m) Rc[m] = Rg[m*4 + c];
    }

    // dot rows hoisted to registers (no LDS for F/H in the loop):
    // lanes<32: row pi(lane) of F (cols plain); lanes>=32: row (lane&3) of H.
    f4v frow[8];
    {
        const float* rowp = (lane < 32) ? (Fg + (size_t)pi(lane)*32)
                                        : (Hg + (size_t)(lane & 3)*32);
        #pragma unroll
        for (int q = 0; q < 8; ++q) frow[q] = *(const f4v*)(rowp + 4*q);
    }
    // sm holds the mean UNPERMUTED; lane c's update lands at sm[pi(c)].
    if (lane < 32) sm[lane] = im[b*32 + lane];

    const bool yl = (lane >= 32 && lane < 36);
    const float* obsp = obs + (size_t)b*TT*4 + (yl ? (lane - 32) : 0);
    float* om = out;
    float* oc = out + (size_t)TT * BB * 4;

    // software-pipelined observation load (consumed one step later)
    float yv = yl ? obsp[0] : 0.f;

    for (int t = 0; t < TT; ++t) {
        // issue next step's obs load NOW; consumed ~full step later
        float yv_nxt = (yl && t + 1 < TT) ? obsp[(t + 1) * 4] : 0.f;

        // lanes<32: (F m)[pi(lane)];  lanes>=32: (H m)[lane&3]
        float dotv = 0.f;
        #pragma unroll
        for (int q = 0; q < 8; ++q) {
            f4v mv = *(const f4v*)&sm[4*q];
            dotv += frow[q].x*mv.x + frow[q].y*mv.y
                  + frow[q].z*mv.z + frow[q].w*mv.w;
        }

        // state operands straight from C-layout regs (no exchange)
        bf8 Dh0, Dl0, Dh1, Dl1;
        packfrag(P, Dh0, Dl0, Dh1, Dl1);

        // U1 = Pi*P*H^T  (cols c>=4 exact zeros) -- critical path first
        f16v pA = 0.0f, pB = 0.0f;
        pA = MFMA(Dh0, Hh[0], pA);  pB = MFMA(Dh1, Hh[1], pB);
        pA = MFMA(Dh0, Hl[0], pA);  pB = MFMA(Dh1, Hl[1], pB);
        pA = MFMA(Dl0, Hh[0], pA);  pB = MFMA(Dl1, Hh[1], pB);

        // T = Pi*P*F^T*Pi
        f16v tA = 0.0f, tB = 0.0f;
        tA = MFMA(Dh0, Fh[0], tA);  tB = MFMA(Dh1, Fh[1], tB);
        tA = MFMA(Dh0, Fl[0], tA);  tB = MFMA(Dh1, Fl[1], tB);
        tA = MFMA(Dl0, Fh[0], tA);  tB = MFMA(Dl1, Fh[1], tB);

        // U1 operands from registers (no exchange)
        f16v Us = pA + pB;
        bf8 Uh0, Ul0, Uh1, Ul1;
        packfrag(Us, Uh0, Ul0, Uh1, Ul1);

        // S = H*P*H^T  (exact)
        f16v sA = 0.0f, sB = 0.0f;
        sA = MFMA(Hh[0], Uh0, sA);  sB = MFMA(Hh[1], Uh1, sB);
        sA = MFMA(Hh[0], Ul0, sA);  sB = MFMA(Hh[1], Ul1, sB);
        sA = MFMA(Hl[0], Uh0, sA);  sB = MFMA(Hl[1], Uh1, sB);

        // Wt = W^T*Pi: lane c (h=0) regs 0-3 hold W'[c][m] = W[pi(c)][m]
        f16v wA = 0.0f, wB = 0.0f;
        wA = MFMA(Uh0, Fh[0], wA);  wB = MFMA(Uh1, Fh[1], wB);
        wA = MFMA(Uh0, Fl[0], wA);  wB = MFMA(Uh1, Fl[1], wB);
        wA = MFMA(Ul0, Fh[0], wA);  wB = MFMA(Ul1, Fh[1], wB);

        // T operands from registers (no exchange)
        f16v Tp = tA + tB;
        bf8 Th0, Tl0, Th1, Tl1;
        packfrag(Tp, Th0, Tl0, Th1, Tl1);

        // Z = hat(F*P*F^T + Q)
        f16v zA = Qc, zB = 0.0f;
        zA = MFMA(Fh[0], Th0, zA);  zB = MFMA(Fh[1], Th1, zB);
        zA = MFMA(Fh[0], Tl0, zA);  zB = MFMA(Fh[1], Tl1, zB);
        zA = MFMA(Fl[0], Th0, zA);  zB = MFMA(Fl[1], Tl1, zB);

        // outputs
        float Smr[4];
        #pragma unroll
        for (int m = 0; m < 4; ++m) Smr[m] = sA[m] + sB[m] + Rc[m];
        if (lane < 32 && c < 4) {
            #pragma unroll
            for (int m = 0; m < 4; ++m)
                oc[(((size_t)t*BB + b)*4 + m)*4 + c] = Smr[m];
        }
        float residv = yv - dotv;                 // valid on lanes 32..35
        if (yl) om[((size_t)t*BB + b)*4 + (lane - 32)] = dotv;

        if (t == TT - 1) break;
        yv = yv_nxt;

        // Smeas broadcast via v_readlane (VALU, no LDS). S(4m+c) = S[m][c].
        const float S0  = rl(Smr[0], 0), S1  = rl(Smr[0], 1),
                    S2  = rl(Smr[0], 2), S3  = rl(Smr[0], 3);
        const float S4  = rl(Smr[1], 0), S5  = rl(Smr[1], 1),
                    S6  = rl(Smr[1], 2), S7  = rl(Smr[1], 3);
        const float S8  = rl(Smr[2], 0), S9  = rl(Smr[2], 1),
                    S10 = rl(Smr[2], 2), S11 = rl(Smr[2], 3);
        const float S12 = rl(Smr[3], 0), S13 = rl(Smr[3], 1),
                    S14 = rl(Smr[3], 2), S15 = rl(Smr[3], 3);

        const float rv0 = rl(residv, 32), rv1 = rl(residv, 33),
                    rv2 = rl(residv, 34), rv3 = rl(residv, 35);

        float nG0, nG1, nG2, nG3, W0, W1, W2, W3;
        {
            const float A2323 = S10*S15 - S11*S14;
            const float A1323 = S9 *S15 - S11*S13;
            const float A1223 = S9 *S14 - S10*S13;
            const float A0323 = S8 *S15 - S11*S12;
            const float A0223 = S8 *S14 - S10*S12;
            const float A0123 = S8 *S13 - S9 *S12;
            const float A2313 = S6 *S15 - S7 *S14;
            const float A1313 = S5 *S15 - S7 *S13;
            const float A1213 = S5 *S14 - S6 *S13;
            const float A2312 = S6 *S11 - S7 *S10;
            const float A1312 = S5 *S11 - S7 *S9;
            const float A1212 = S5 *S10 - S6 *S9;
            const float A0313 = S4 *S15 - S7 *S12;
            const float A0213 = S4 *S14 - S6 *S12;
            const float A0312 = S4 *S11 - S7 *S8;
            const float A0212 = S4 *S10 - S6 *S8;
            const float A0113 = S4 *S13 - S5 *S12;
            const float A0112 = S4 *S9  - S5 *S8;

            const float i00 =  (S5*A2323 - S6*A1323 + S7*A1223);
            const float i10 = -(S4*A2323 - S6*A0323 + S7*A0223);
            const float i20 =  (S4*A1323 - S5*A0323 + S7*A0123);
            const float i30 = -(S4*A1223 - S5*A0223 + S6*A0123);
            const float i01 = -(S1*A2323 - S2*A1323 + S3*A1223);
            const float i11 =  (S0*A2323 - S2*A0323 + S3*A0223);
            const float i21 = -(S0*A1323 - S1*A0323 + S3*A0123);
            const float i31 =  (S0*A1223 - S1*A0223 + S2*A0123);
            const float i02 =  (S1*A2313 - S2*A1313 + S3*A1213);
            const float i12 = -(S0*A2313 - S2*A0313 + S3*A0213);
            const float i22 =  (S0*A1313 - S1*A0313 + S3*A0113);
            const float i32 = -(S0*A1213 - S1*A0213 + S2*A0113);
            const float i03 = -(S1*A2312 - S2*A1312 + S3*A1212);
            const float i13 =  (S0*A2312 - S2*A0312 + S3*A0212);
            const float i23 = -(S0*A1312 - S1*A0312 + S3*A0112);
            const float i33 =  (S0*A1212 - S1*A0212 + S2*A0112);

            const float det = S0*i00 + S1*i10 + S2*i20 + S3*i30;
            const float nid = -1.0f / det;   // nG = -W*Sinv

            W0 = wA[0] + wB[0];
            W1 = wA[1] + wB[1];
            W2 = wA[2] + wB[2];
            W3 = wA[3] + wB[3];

            nG0 = nid * (W0*i00 + W1*i10 + W2*i20 + W3*i30);
            nG1 = nid * (W0*i01 + W1*i11 + W2*i21 + W3*i31);
            nG2 = nid * (W0*i02 + W1*i12 + W2*i22 + W3*i32);
            nG3 = nid * (W0*i03 + W1*i13 + W2*i23 + W3*i33);
        }

        // rank-4 correction in hat space: corr = (Pi nG)(Pi W)^T
        // (h==1 lanes have W'=0 -> nG'=0 -> contribute zeros)
        bf8 Gh = (bf8)(short)0, Gl = (bf8)(short)0;
        bf8 Wbh = (bf8)(short)0, Wbl = (bf8)(short)0;
        {
            float ng[4] = {nG0, nG1, nG2, nG3};
            float wv[4] = {W0, W1, W2, W3};
            #pragma unroll
            for (int j2 = 0; j2 < 4; ++j2) {
                short hi, lo;
                tsplit(ng[j2], hi, lo);
                Gh[j2] = hi; Gl[j2] = lo;
                tsplit(wv[j2], hi, lo);
                Wbh[j2] = hi; Wbl[j2] = lo;
            }
        }
        f16v Pn = zA + zB;
        Pn = MFMA(Gh, Wbh, Pn);
        Pn = MFMA(Gh, Wbl, Pn);
        Pn = MFMA(Gl, Wbh, Pn);
        P = Pn;

        // mean: lane c computes m'[pi(c)] = (Fm)[pi(c)] - nG[pi(c)].resid
        // and stores it at sm[pi(c)] so sm stays unpermuted.
        if (lane < 32)
            sm[pi(lane)] = dotv - (nG0*rv0 + nG1*rv1 + nG2*rv2 + nG3*rv3);
    }
}

extern "C" void kernel_launch(void* const* d_in, const int* in_sizes, int n_in,
                              void* d_out, int out_size, void* d_ws, size_t ws_size,
                              hipStream_t stream) {
    const float* obs       = (const float*)d_in[0];
    const float* F         = (const float*)d_in[1];
    const float* Q         = (const float*)d_in[2];
    const float* H         = (const float*)d_in[3];
    const float* R         = (const float*)d_in[4];
    const float* init_mean = (const float*)d_in[5];
    const float* init_cov  = (const float*)d_in[6];
    float* out = (float*)d_out;

    kalman_v8<<<BB, 64, 0, stream>>>(obs, F, Q, H, R, init_mean, init_cov, out);
}

// Round 4
// 421.903 us; speedup vs baseline: 1.3832x; 1.1383x over previous
//
#include <hip/hip_runtime.h>

#define BB 512
#define TT 256

typedef __attribute__((ext_vector_type(8)))  short bf8;   // 8 bf16 in 4 VGPRs
typedef __attribute__((ext_vector_type(16))) float f16v;  // MFMA 32x32 acc
typedef __attribute__((ext_vector_type(4)))  float f4v;

#define MFMA(a,b,c) __builtin_amdgcn_mfma_f32_32x32x16_bf16((a),(b),(c),0,0,0)

static __device__ __forceinline__ unsigned short f2bf_rne(float x) {
    unsigned u = __builtin_bit_cast(unsigned, x);
    return (unsigned short)((u + 0x7FFFu + ((u >> 16) & 1u)) >> 16);
}
static __device__ __forceinline__ float bf2f(unsigned short h) {
    unsigned u = ((unsigned)h) << 16;
    return __builtin_bit_cast(float, u);
}
// truncation-based hi/lo split: |x - (hi+lo)| <~ 2^-17 |x|
static __device__ __forceinline__ void tsplit(float x, short& hi, short& lo) {
    unsigned u = __builtin_bit_cast(unsigned, x);
    hi = (short)(u >> 16);
    float hf = __builtin_bit_cast(float, u & 0xFFFF0000u);
    float l  = x - hf;
    lo = (short)(__builtin_bit_cast(unsigned, l) >> 16);
}
// pi = swap bits 2 and 3 of a 5-bit row index (involution).
// C-layout(D) with reg (j+8kk) as frag elem j of kk == A-frag of D^T*Pi
// (same lane, same h -- zero cross-lane movement). As B-frag, the product
// rule is  MFMA(A, D-as-B) = A * Pi * D.
static __device__ __forceinline__ int pi(int i) {
    return (i & ~12) | ((i & 4) << 1) | ((i & 8) >> 1);
}
static __device__ __forceinline__ float rl(float x, int l) {
    return __builtin_bit_cast(float,
        __builtin_amdgcn_readlane(__builtin_bit_cast(unsigned, x), l));
}
// C-layout f32 (16 regs) -> bf16 hi/lo A/B operands; reg j+8kk -> elem j of kk.
static __device__ __forceinline__ void packfrag(const f16v X,
        bf8& h0, bf8& l0, bf8& h1, bf8& l1) {
    #pragma unroll
    for (int j = 0; j < 8; ++j) {
        short hi, lo;
        tsplit(X[j],     hi, lo);  h0[j] = hi;  l0[j] = lo;
        tsplit(X[8 + j], hi, lo);  h1[j] = hi;  l1[j] = lo;
    }
}

// One chain per wave; single-wave block => no __syncthreads anywhere.
// Step:  P_p = (F P F^T + Q) - W Sinv W^T,  W = F P H^T.
// v9 = v8 (Pi-similarity space, zero cross-lane on P-path) plus:
//   - single accumulator per stage (acc-chained MFMA is full rate); corr
//     chains into the Z acc; S acc initialized from C-layout R (folds +R)
//   - W computed from T (W^T*Pi = H*Pi*T), off the U1->S->Cramer arm
//   - symmetric-S Cramer (10 cofactors, 14 minors, 10 S-readlanes)
//   - Z-stage lo-arm bug fixed (v7/v8 had Fl[1]*Tl1 instead of Fl[1]*Th1)
__global__ __launch_bounds__(64, 1)
void kalman_v9(const float* __restrict__ obs,
               const float* __restrict__ Fg,
               const float* __restrict__ Qg,
               const float* __restrict__ Hg,
               const float* __restrict__ Rg,
               const float* __restrict__ im,
               const float* __restrict__ ic,
               float* __restrict__ out)
{
    __shared__ __align__(16) float sm[32];

    const int lane = threadIdx.x;
    const int b    = blockIdx.x;
    const int c    = lane & 31;
    const int h    = lane >> 5;

    // PiF (rows pi-permuted, cols plain) -- dual-use as A-frag and B-frag.
    // H plain (rows c<4).
    bf8 Fh[2], Fl[2], Hh[2], Hl[2];
    #pragma unroll
    for (int kk = 0; kk < 2; ++kk) {
        #pragma unroll
        for (int j = 0; j < 8; ++j) {
            int k = kk*16 + h*8 + j;
            float f = Fg[pi(c)*32 + k];
            unsigned short fh = f2bf_rne(f);
            Fh[kk][j] = (short)fh;
            Fl[kk][j] = (short)f2bf_rne(f - bf2f(fh));
            float hv = (c < 4) ? Hg[c*32 + k] : 0.f;
            unsigned short hh = f2bf_rne(hv);
            Hh[kk][j] = (short)hh;
            Hl[kk][j] = (short)f2bf_rne(hv - bf2f(hh));
        }
    }

    // state P := hat(init_cov), Qc := hat(Q) in C-layout; Rcl := R in C-layout
    // (nonzero only rows<4 x cols<4, i.e. h==0, reg<4, c<4).
    f16v Qc, P, Rcl;
    #pragma unroll
    for (int reg = 0; reg < 16; ++reg) {
        int row = (reg & 3) + 8*(reg >> 2) + 4*h;
        Qc[reg]  = Qg[pi(row)*32 + pi(c)];
        P[reg]   = ic[(size_t)b*1024 + pi(row)*32 + pi(c)];
        Rcl[reg] = (reg < 4 && h == 0 && c < 4) ? Rg[reg*4 + c] : 0.f;
    }

    // dot rows hoisted to registers:
    // lanes<32: row pi(lane) of F; lanes>=32: row (lane&3) of H.
    f4v frow[8];
    {
        const float* rowp = (lane < 32) ? (Fg + (size_t)pi(lane)*32)
                                        : (Hg + (size_t)(lane & 3)*32);
        #pragma unroll
        for (int q = 0; q < 8; ++q) frow[q] = *(const f4v*)(rowp + 4*q);
    }
    // sm holds the mean UNPERMUTED; lane c's update lands at sm[pi(c)].
    if (lane < 32) sm[lane] = im[b*32 + lane];

    const bool yl = (lane >= 32 && lane < 36);
    const float* obsp = obs + (size_t)b*TT*4 + (yl ? (lane - 32) : 0);
    float* om = out;
    float* oc = out + (size_t)TT * BB * 4;

    // software-pipelined observation load (consumed one step later)
    float yv = yl ? obsp[0] : 0.f;

    for (int t = 0; t < TT; ++t) {
        // issue next step's obs load NOW; consumed ~full step later
        float yv_nxt = (yl && t + 1 < TT) ? obsp[(t + 1) * 4] : 0.f;

        // lanes<32: (F m)[pi(lane)];  lanes>=32: (H m)[lane&3]
        float dotv = 0.f;
        #pragma unroll
        for (int q = 0; q < 8; ++q) {
            f4v mv = *(const f4v*)&sm[4*q];
            dotv += frow[q].x*mv.x + frow[q].y*mv.y
                  + frow[q].z*mv.z + frow[q].w*mv.w;
        }

        // state operands straight from C-layout regs (no exchange)
        bf8 Dh0, Dl0, Dh1, Dl1;
        packfrag(P, Dh0, Dl0, Dh1, Dl1);

        // U1 = Pi*P*H^T  (cols c>=4 exact zeros) -- single acc, 6 chained
        f16v uacc = 0.0f;
        uacc = MFMA(Dh0, Hh[0], uacc);  uacc = MFMA(Dh1, Hh[1], uacc);
        uacc = MFMA(Dh0, Hl[0], uacc);  uacc = MFMA(Dh1, Hl[1], uacc);
        uacc = MFMA(Dl0, Hh[0], uacc);  uacc = MFMA(Dl1, Hh[1], uacc);

        // T = Pi*P*F^T*Pi
        f16v tacc = 0.0f;
        tacc = MFMA(Dh0, Fh[0], tacc);  tacc = MFMA(Dh1, Fh[1], tacc);
        tacc = MFMA(Dh0, Fl[0], tacc);  tacc = MFMA(Dh1, Fl[1], tacc);
        tacc = MFMA(Dl0, Fh[0], tacc);  tacc = MFMA(Dl1, Fh[1], tacc);

        // U1 operands from registers
        bf8 Uh0, Ul0, Uh1, Ul1;
        packfrag(uacc, Uh0, Ul0, Uh1, Ul1);

        // S = H*Pi*U1 + R = H*P*H^T + R  (acc starts at C-layout R)
        f16v sacc = Rcl;
        sacc = MFMA(Hh[0], Uh0, sacc);  sacc = MFMA(Hh[1], Uh1, sacc);
        sacc = MFMA(Hh[0], Ul0, sacc);  sacc = MFMA(Hh[1], Ul1, sacc);
        sacc = MFMA(Hl[0], Uh0, sacc);  sacc = MFMA(Hl[1], Uh1, sacc);

        // T operands from registers
        bf8 Th0, Tl0, Th1, Tl1;
        packfrag(tacc, Th0, Tl0, Th1, Tl1);

        // Wt = H*Pi*T = H*P*F^T*Pi = W^T*Pi: lane c regs 0-3 = W[pi(c)][m]
        f16v wacc = 0.0f;
        wacc = MFMA(Hh[0], Th0, wacc);  wacc = MFMA(Hh[1], Th1, wacc);
        wacc = MFMA(Hh[0], Tl0, wacc);  wacc = MFMA(Hh[1], Tl1, wacc);
        wacc = MFMA(Hl[0], Th0, wacc);  wacc = MFMA(Hl[1], Th1, wacc);

        // Z = PiF*Pi*T + hatQ = hat(F*P*F^T + Q); corr chains in later
        f16v zacc = Qc;
        zacc = MFMA(Fh[0], Th0, zacc);  zacc = MFMA(Fh[1], Th1, zacc);
        zacc = MFMA(Fh[0], Tl0, zacc);  zacc = MFMA(Fh[1], Tl1, zacc);
        zacc = MFMA(Fl[0], Th0, zacc);  zacc = MFMA(Fl[1], Th1, zacc);

        // outputs
        if (lane < 32 && c < 4) {
            #pragma unroll
            for (int m = 0; m < 4; ++m)
                oc[(((size_t)t*BB + b)*4 + m)*4 + c] = sacc[m];
        }
        float residv = yv - dotv;                 // valid on lanes 32..35
        if (yl) om[((size_t)t*BB + b)*4 + (lane - 32)] = dotv;

        if (t == TT - 1) break;
        yv = yv_nxt;

        // S lower triangle via v_readlane (S symmetric): sacc[m] on lane n = S[m][n]
        const float sa = rl(sacc[0], 0);
        const float sb = rl(sacc[1], 0), se = rl(sacc[1], 1);
        const float sc = rl(sacc[2], 0), sf = rl(sacc[2], 1), sh = rl(sacc[2], 2);
        const float sd = rl(sacc[3], 0), sg = rl(sacc[3], 1), si = rl(sacc[3], 2),
                    sj = rl(sacc[3], 3);

        const float rv0 = rl(residv, 32), rv1 = rl(residv, 33),
                    rv2 = rl(residv, 34), rv3 = rl(residv, 35);

        float nG0, nG1, nG2, nG3, W0, W1, W2, W3;
        {
            // symmetric 4x4 inverse: 14 unique 2x2 minors, 10 cofactors
            const float m1  = sh*sj - si*si;
            const float m2  = sf*sj - sg*si;
            const float m3  = sf*si - sg*sh;
            const float m4  = sc*sj - sd*si;
            const float m5  = sc*si - sd*sh;
            const float m6  = sc*sg - sd*sf;
            const float m7  = se*sj - sg*sg;
            const float m8  = sb*sj - sd*sg;
            const float m9  = sb*sg - se*sd;
            const float m10 = se*si - sf*sg;
            const float m11 = sb*si - sd*sf;
            const float m12 = se*sh - sf*sf;
            const float m13 = sb*sh - sc*sf;
            const float m14 = sb*sf - sc*se;

            const float C00 =   se*m1 - sf*m2 + sg*m3;
            const float C01 = -(sb*m1 - sf*m4 + sg*m5);
            const float C02 =   sb*m2 - se*m4 + sg*m6;
            const float C03 = -(sb*m3 - se*m5 + sf*m6);
            const float C11 =   sa*m1 - sc*m4 + sd*m5;
            const float C12 = -(sa*m2 - sb*m4 + sd*m6);
            const float C13 =   sa*m3 - sb*m5 + sc*m6;
            const float C22 =   sa*m7 - sb*m8 + sd*m9;
            const float C23 = -(sa*m10 - sb*m11 + sc*m9);
            const float C33 =   sa*m12 - sb*m13 + sc*m14;

            const float det = sa*C00 + sb*C01 + sc*C02 + sd*C03;
            const float nid = -1.0f / det;   // nG = -W*Sinv

            W0 = wacc[0];
            W1 = wacc[1];
            W2 = wacc[2];
            W3 = wacc[3];

            nG0 = nid * (W0*C00 + W1*C01 + W2*C02 + W3*C03);
            nG1 = nid * (W0*C01 + W1*C11 + W2*C12 + W3*C13);
            nG2 = nid * (W0*C02 + W1*C12 + W2*C22 + W3*C23);
            nG3 = nid * (W0*C03 + W1*C13 + W2*C23 + W3*C33);
        }

        // rank-4 correction in hat space: corr = (Pi nG)(Pi W)^T, chained
        // into zacc (h==1 lanes have W'=0 -> nG'=0 -> contribute zeros)
        bf8 Gh = (bf8)(short)0, Gl = (bf8)(short)0;
        bf8 Wbh = (bf8)(short)0, Wbl = (bf8)(short)0;
        {
            float ng[4] = {nG0, nG1, nG2, nG3};
            float wv[4] = {W0, W1, W2, W3};
            #pragma unroll
            for (int j2 = 0; j2 < 4; ++j2) {
                short hi, lo;
                tsplit(ng[j2], hi, lo);
                Gh[j2] = hi; Gl[j2] = lo;
                tsplit(wv[j2], hi, lo);
                Wbh[j2] = hi; Wbl[j2] = lo;
            }
        }
        zacc = MFMA(Gh, Wbh, zacc);
        zacc = MFMA(Gh, Wbl, zacc);
        zacc = MFMA(Gl, Wbh, zacc);
        P = zacc;

        // mean: lane c computes m'[pi(c)] = (Fm)[pi(c)] - nG[pi(c)].resid
        // and stores at sm[pi(c)] so sm stays unpermuted.
        if (lane < 32)
            sm[pi(lane)] = dotv - (nG0*rv0 + nG1*rv1 + nG2*rv2 + nG3*rv3);
    }
}

extern "C" void kernel_launch(void* const* d_in, const int* in_sizes, int n_in,
                              void* d_out, int out_size, void* d_ws, size_t ws_size,
                              hipStream_t stream) {
    const float* obs       = (const float*)d_in[0];
    const float* F         = (const float*)d_in[1];
    const float* Q         = (const float*)d_in[2];
    const float* H         = (const float*)d_in[3];
    const float* R         = (const float*)d_in[4];
    const float* init_mean = (const float*)d_in[5];
    const float* init_cov  = (const float*)d_in[6];
    float* out = (float*)d_out;

    kalman_v9<<<BB, 64, 0, stream>>>(obs, F, Q, H, R, init_mean, init_cov, out);
}